// Round 1
// baseline (116.053 us; speedup 1.0000x reference)
//
#include <hip/hip_runtime.h>

// PairwiseLoss: weighted 2-class cross-entropy + top-1 accuracy over all
// probe×gallery pairs.
//   labels[i,j] = (tp[i]==tg[j]); logits[i,j,:] = cls_encode[i,j,0:2]
//   loss = sum(w*nll)/sum(w),  w = label ? 1 : 1/4095
//   prec = 100 * mean(argmax(logits)==label)
// Memory-bound: 4096*4096*2*4B = 134 MB read once.

constexpr int BATCH = 4096;
constexpr float W_NEG_F = 1.0f / 4095.0f;  // matches fp32 W_NEG in reference

// ---------------- kernel 1: per-row partials (deterministic) ----------------
__global__ __launch_bounds__(256) void pl_partials(
    const float* __restrict__ logits,   // [BATCH*BATCH*2]
    const int* __restrict__ tp,         // [BATCH]
    const int* __restrict__ tg,         // [BATCH]
    double* __restrict__ part_wnll,     // [BATCH]
    int* __restrict__ part_pos,         // [BATCH]
    int* __restrict__ part_cor)         // [BATCH]
{
    __shared__ int s_tg[BATCH];         // 16 KiB
    const int t = threadIdx.x;
    const int row = blockIdx.x;

    // stage gallery targets into LDS (vectorized)
    {
        const int4* tg4 = reinterpret_cast<const int4*>(tg);
        int4* s4 = reinterpret_cast<int4*>(s_tg);
        for (int v = t; v < BATCH / 4; v += 256) s4[v] = tg4[v];
    }
    __syncthreads();

    const int my = tp[row];
    const float4* rowp =
        reinterpret_cast<const float4*>(logits) + (size_t)row * (BATCH / 2);

    float wnll = 0.f;
    int pos = 0, cor = 0;

    // 4096 pairs = 2048 float4; 256 threads -> 8 fully-coalesced iterations
#pragma unroll
    for (int k = 0; k < (BATCH / 2) / 256; ++k) {
        const int v = t + k * 256;
        const float4 q = rowp[v];
        const int j = 2 * v;
        const int lab0 = (my == s_tg[j]) ? 1 : 0;
        const int lab1 = (my == s_tg[j + 1]) ? 1 : 0;

        // pair 0: logits (q.x, q.y)
        {
            const float lt = lab0 ? q.y : q.x;   // logit of true class
            const float lo = lab0 ? q.x : q.y;   // logit of other class
            const float d = lo - lt;
            const float nll = (d > 0.f) ? d + log1pf(expf(-d)) : log1pf(expf(d));
            wnll += (lab0 ? 1.0f : W_NEG_F) * nll;
            pos += lab0;
            const int pred = (q.y > q.x) ? 1 : 0;  // argmax, first-index ties
            cor += (pred == lab0) ? 1 : 0;
        }
        // pair 1: logits (q.z, q.w)
        {
            const float lt = lab1 ? q.w : q.z;
            const float lo = lab1 ? q.z : q.w;
            const float d = lo - lt;
            const float nll = (d > 0.f) ? d + log1pf(expf(-d)) : log1pf(expf(d));
            wnll += (lab1 ? 1.0f : W_NEG_F) * nll;
            pos += lab1;
            const int pred = (q.w > q.z) ? 1 : 0;
            cor += (pred == lab1) ? 1 : 0;
        }
    }

    // wave64 shuffle reduce (double for wnll)
    double dw = (double)wnll;
#pragma unroll
    for (int off = 32; off > 0; off >>= 1) {
        dw += __shfl_down(dw, off);
        pos += __shfl_down(pos, off);
        cor += __shfl_down(cor, off);
    }
    __shared__ double s_dw[4];
    __shared__ int s_pos[4], s_cor[4];
    const int wave = t >> 6, lane = t & 63;
    if (lane == 0) { s_dw[wave] = dw; s_pos[wave] = pos; s_cor[wave] = cor; }
    __syncthreads();
    if (t == 0) {
        part_wnll[row] = s_dw[0] + s_dw[1] + s_dw[2] + s_dw[3];
        part_pos[row] = s_pos[0] + s_pos[1] + s_pos[2] + s_pos[3];
        part_cor[row] = s_cor[0] + s_cor[1] + s_cor[2] + s_cor[3];
    }
}

// ---------------- kernel 2: fixed-order final reduce ----------------
__global__ __launch_bounds__(256) void pl_final(
    const double* __restrict__ part_wnll,
    const int* __restrict__ part_pos,
    const int* __restrict__ part_cor,
    float* __restrict__ out)            // out[0]=loss, out[1]=prec
{
    const int t = threadIdx.x;
    double dw = 0.0;
    long long pos = 0, cor = 0;
    for (int v = t; v < BATCH; v += 256) {
        dw += part_wnll[v];
        pos += (long long)part_pos[v];
        cor += (long long)part_cor[v];
    }
#pragma unroll
    for (int off = 32; off > 0; off >>= 1) {
        dw += __shfl_down(dw, off);
        pos += __shfl_down(pos, off);
        cor += __shfl_down(cor, off);
    }
    __shared__ double s_dw[4];
    __shared__ long long s_pos[4], s_cor[4];
    const int wave = t >> 6, lane = t & 63;
    if (lane == 0) { s_dw[wave] = dw; s_pos[wave] = pos; s_cor[wave] = cor; }
    __syncthreads();
    if (t == 0) {
        const double tot = s_dw[0] + s_dw[1] + s_dw[2] + s_dw[3];
        const long long P = s_pos[0] + s_pos[1] + s_pos[2] + s_pos[3];
        const long long C = s_cor[0] + s_cor[1] + s_cor[2] + s_cor[3];
        const double NP = (double)BATCH * (double)BATCH;
        // sum_w is exact given the positive count
        const double sum_w = (double)P + (NP - (double)P) * (double)W_NEG_F;
        out[0] = (float)(tot / sum_w);
        out[1] = (float)(100.0 * (double)C / NP);
    }
}

extern "C" void kernel_launch(void* const* d_in, const int* in_sizes, int n_in,
                              void* d_out, int out_size, void* d_ws, size_t ws_size,
                              hipStream_t stream) {
    const float* logits = (const float*)d_in[0];  // cls_encode [4096,4096,2] f32
    const int* tp = (const int*)d_in[1];          // tar_probe  [4096] i32
    const int* tg = (const int*)d_in[2];          // tar_gallery[4096] i32
    float* out = (float*)d_out;                   // [loss, prec]

    // workspace layout: 4096 doubles | 4096 ints | 4096 ints  (48 KiB)
    double* part_wnll = (double*)d_ws;
    int* part_pos = (int*)((char*)d_ws + BATCH * sizeof(double));
    int* part_cor = part_pos + BATCH;

    pl_partials<<<BATCH, 256, 0, stream>>>(logits, tp, tg, part_wnll, part_pos,
                                           part_cor);
    pl_final<<<1, 256, 0, stream>>>(part_wnll, part_pos, part_cor, out);
}

// Round 2
// 33.117 us; speedup vs baseline: 3.5043x; 3.5043x over previous
//
#include <hip/hip_runtime.h>

// PairwiseLoss: weighted 2-class cross-entropy + top-1 accuracy over all
// probe×gallery pairs.
//   labels[i,j] = (tp[i]==tg[j]); logits[i,j,:] = cls_encode[i,j,0:2]
//   loss = sum(w*nll)/sum(w),  w = label ? 1 : 1/4095
//   prec = 100 * mean(argmax(logits)==label)
//
// R1 lesson: libm log1pf/expf in a predicated ternary = ~540 VALU ops/pair
// (VALUBusy 100%, 7% HBM). R2: branch-free softplus via __expf/__logf
// hardware intrinsics, weight factored out of the loop:
//   w*nll summed == W_NEG*sum_all_nll + (1-W_NEG)*sum_pos_nll

constexpr int BATCH = 4096;
constexpr float W_NEG_F = 1.0f / 4095.0f;  // matches fp32 W_NEG in reference

// ---------------- kernel 1: per-row partials (deterministic) ----------------
__global__ __launch_bounds__(256) void pl_partials(
    const float* __restrict__ logits,   // [BATCH*BATCH*2]
    const int* __restrict__ tp,         // [BATCH]
    const int* __restrict__ tg,         // [BATCH]
    double* __restrict__ part_wnll,     // [BATCH]
    int* __restrict__ part_pos,         // [BATCH]
    int* __restrict__ part_cor)         // [BATCH]
{
    __shared__ int s_tg[BATCH];         // 16 KiB
    const int t = threadIdx.x;
    const int row = blockIdx.x;

    // stage gallery targets into LDS (vectorized)
    {
        const int4* tg4 = reinterpret_cast<const int4*>(tg);
        int4* s4 = reinterpret_cast<int4*>(s_tg);
        for (int v = t; v < BATCH / 4; v += 256) s4[v] = tg4[v];
    }
    __syncthreads();

    const int my = tp[row];
    const float4* rowp =
        reinterpret_cast<const float4*>(logits) + (size_t)row * (BATCH / 2);

    float sum_all = 0.f;   // sum of nll over all pairs this thread sees
    float sum_pos = 0.f;   // sum of nll over positive pairs only
    int pos = 0, cor = 0;

    // 4096 pairs = 2048 float4; 256 threads -> 8 fully-coalesced iterations
#pragma unroll
    for (int k = 0; k < (BATCH / 2) / 256; ++k) {
        const int v = t + k * 256;
        const float4 q = rowp[v];
        const int2 g = *reinterpret_cast<const int2*>(&s_tg[2 * v]);
        const bool lab0 = (my == g.x);
        const bool lab1 = (my == g.y);

        // pair 0: logits (q.x, q.y); d = logit_other - logit_true
        {
            const float e = q.y - q.x;            // d when lab==0
            const float d = lab0 ? -e : e;
            // softplus(d) = max(d,0) + log(1+exp(-|d|)), branch-free HW instrs
            const float nll = fmaxf(d, 0.f) + __logf(1.f + __expf(-fabsf(d)));
            sum_all += nll;
            sum_pos += lab0 ? nll : 0.f;
            pos += lab0 ? 1 : 0;
            const bool pred = (q.y > q.x);        // argmax, first-index ties
            cor += (pred == lab0) ? 1 : 0;
        }
        // pair 1: logits (q.z, q.w)
        {
            const float e = q.w - q.z;
            const float d = lab1 ? -e : e;
            const float nll = fmaxf(d, 0.f) + __logf(1.f + __expf(-fabsf(d)));
            sum_all += nll;
            sum_pos += lab1 ? nll : 0.f;
            pos += lab1 ? 1 : 0;
            const bool pred = (q.w > q.z);
            cor += (pred == lab1) ? 1 : 0;
        }
    }

    // weighted combination, then wave64 shuffle reduce in double
    double dw = (double)W_NEG_F * (double)sum_all +
                (1.0 - (double)W_NEG_F) * (double)sum_pos;
#pragma unroll
    for (int off = 32; off > 0; off >>= 1) {
        dw += __shfl_down(dw, off);
        pos += __shfl_down(pos, off);
        cor += __shfl_down(cor, off);
    }
    __shared__ double s_dw[4];
    __shared__ int s_pos[4], s_cor[4];
    const int wave = t >> 6, lane = t & 63;
    if (lane == 0) { s_dw[wave] = dw; s_pos[wave] = pos; s_cor[wave] = cor; }
    __syncthreads();
    if (t == 0) {
        part_wnll[row] = s_dw[0] + s_dw[1] + s_dw[2] + s_dw[3];
        part_pos[row] = s_pos[0] + s_pos[1] + s_pos[2] + s_pos[3];
        part_cor[row] = s_cor[0] + s_cor[1] + s_cor[2] + s_cor[3];
    }
}

// ---------------- kernel 2: fixed-order final reduce ----------------
__global__ __launch_bounds__(256) void pl_final(
    const double* __restrict__ part_wnll,
    const int* __restrict__ part_pos,
    const int* __restrict__ part_cor,
    float* __restrict__ out)            // out[0]=loss, out[1]=prec
{
    const int t = threadIdx.x;
    double dw = 0.0;
    long long pos = 0, cor = 0;
    for (int v = t; v < BATCH; v += 256) {
        dw += part_wnll[v];
        pos += (long long)part_pos[v];
        cor += (long long)part_cor[v];
    }
#pragma unroll
    for (int off = 32; off > 0; off >>= 1) {
        dw += __shfl_down(dw, off);
        pos += __shfl_down(pos, off);
        cor += __shfl_down(cor, off);
    }
    __shared__ double s_dw[4];
    __shared__ long long s_pos[4], s_cor[4];
    const int wave = t >> 6, lane = t & 63;
    if (lane == 0) { s_dw[wave] = dw; s_pos[wave] = pos; s_cor[wave] = cor; }
    __syncthreads();
    if (t == 0) {
        const double tot = s_dw[0] + s_dw[1] + s_dw[2] + s_dw[3];
        const long long P = s_pos[0] + s_pos[1] + s_pos[2] + s_pos[3];
        const long long C = s_cor[0] + s_cor[1] + s_cor[2] + s_cor[3];
        const double NP = (double)BATCH * (double)BATCH;
        // sum_w is exact given the positive count
        const double sum_w = (double)P + (NP - (double)P) * (double)W_NEG_F;
        out[0] = (float)(tot / sum_w);
        out[1] = (float)(100.0 * (double)C / NP);
    }
}

extern "C" void kernel_launch(void* const* d_in, const int* in_sizes, int n_in,
                              void* d_out, int out_size, void* d_ws, size_t ws_size,
                              hipStream_t stream) {
    const float* logits = (const float*)d_in[0];  // cls_encode [4096,4096,2] f32
    const int* tp = (const int*)d_in[1];          // tar_probe  [4096] i32
    const int* tg = (const int*)d_in[2];          // tar_gallery[4096] i32
    float* out = (float*)d_out;                   // [loss, prec]

    // workspace layout: 4096 doubles | 4096 ints | 4096 ints  (48 KiB)
    double* part_wnll = (double*)d_ws;
    int* part_pos = (int*)((char*)d_ws + BATCH * sizeof(double));
    int* part_cor = part_pos + BATCH;

    pl_partials<<<BATCH, 256, 0, stream>>>(logits, tp, tg, part_wnll, part_pos,
                                           part_cor);
    pl_final<<<1, 256, 0, stream>>>(part_wnll, part_pos, part_cor, out);
}